// Round 2
// baseline (110.518 us; speedup 1.0000x reference)
//
#include <hip/hip_runtime.h>
#include <stdint.h>

// Problem constants
#define NSLICE 64          // B*C = 16*4
#define N_ELEM 262144      // D*H*W = 64^3 per slice
#define K_TOP  131072      // ceil(0.5*N)
#define INV_KB (1.0f / (131072.0f * 16.0f))   // 1/(K_TOP * B)

#define NB1    2048        // buckets: bits 30..20 of bits(|d|)  (sign masked)
#define SHIFT1 20
#define CPB    32          // blocks per slice  -> 64*32 = 2048 blocks = 8/CU
#define CHUNK  (N_ELEM / CPB)   // 8192 elements per block
#define BLK    256

__device__ __forceinline__ unsigned int absbits(float d) {
    return __float_as_uint(d) & 0x7fffffffu;
}

// ---- Fused pass: per-slice {count, sumsq} histogram over 2048 buckets -----
__global__ __launch_bounds__(BLK) void k_hist(const float* __restrict__ in,
                                              const float* __restrict__ lab,
                                              unsigned int* __restrict__ histC,
                                              float* __restrict__ histS) {
    __shared__ unsigned int hc[NB1];
    __shared__ float hs[NB1];
    const int tid = threadIdx.x;
#pragma unroll
    for (int i = tid; i < NB1; i += BLK) { hc[i] = 0u; hs[i] = 0.0f; }
    __syncthreads();

    const int slice = blockIdx.y;
    const long base = (long)slice * N_ELEM + (long)blockIdx.x * CHUNK;
    const float4* a4 = (const float4*)(in + base);
    const float4* b4 = (const float4*)(lab + base);
    const int nv = CHUNK / 4;  // 2048 quads, 8 per thread

    for (int i = tid; i < nv; i += 2 * BLK) {
        float4 a0 = a4[i];
        float4 b0 = b4[i];
        float4 a1 = a4[i + BLK];
        float4 b1 = b4[i + BLK];

        float d[8] = {a0.x - b0.x, a0.y - b0.y, a0.z - b0.z, a0.w - b0.w,
                      a1.x - b1.x, a1.y - b1.y, a1.z - b1.z, a1.w - b1.w};
#pragma unroll
        for (int j = 0; j < 8; ++j) {
            unsigned int p = absbits(d[j]) >> SHIFT1;   // 0..2047
            atomicAdd(&hc[p], 1u);
            atomicAdd(&hs[p], d[j] * d[j]);
        }
    }
    __syncthreads();

    unsigned int* gc = histC + (long)slice * NB1;
    float* gs = histS + (long)slice * NB1;
#pragma unroll
    for (int i = tid; i < NB1; i += BLK) {
        unsigned int c = hc[i];
        if (c) {
            atomicAdd(&gc[i], c);
            atomicAdd(&gs[i], hs[i]);
        }
    }
}

// ---- Select + finalize: suffix scan from top, interpolate partial bucket --
__global__ __launch_bounds__(BLK) void k_select(const unsigned int* __restrict__ histC,
                                                const float* __restrict__ histS,
                                                float* __restrict__ out) {
    const int slice = blockIdx.x;
    const unsigned int* gc = histC + (long)slice * NB1;
    const float* gs = histS + (long)slice * NB1;
    __shared__ unsigned int partC[BLK];
    __shared__ float partS[BLK];
    __shared__ unsigned int prefC[BLK];
    __shared__ float prefS[BLK];
    const int t = threadIdx.x;
    const int G = NB1 / BLK;  // 8 buckets per thread, descending order
    unsigned int locC[NB1 / BLK];
    float locS[NB1 / BLK];
    unsigned int sc = 0;
    float ss = 0.0f;
#pragma unroll
    for (int j = 0; j < G; ++j) {
        int idx = NB1 - 1 - (t * G + j);
        locC[j] = gc[idx];
        locS[j] = gs[idx];
        sc += locC[j];
        ss += locS[j];
    }
    partC[t] = sc;
    partS[t] = ss;
    __syncthreads();
    if (t == 0) {
        unsigned int c = 0;
        float s = 0.0f;
        for (int i = 0; i < BLK; ++i) {
            prefC[i] = c; prefS[i] = s;
            c += partC[i]; s += partS[i];
        }
    }
    __syncthreads();
    unsigned int cum = prefC[t];
    float sAbove = prefS[t];
#pragma unroll
    for (int j = 0; j < G; ++j) {
        unsigned int nc = cum + locC[j];
        if (cum < K_TOP && nc >= K_TOP) {
            const unsigned int p = (unsigned int)(NB1 - 1 - (t * G + j));
            const unsigned int r = K_TOP - cum;          // 1..c
            const unsigned int c = locC[j];
            const float m = locS[j] / (float)c;          // mean square in bucket
            const float lo = __uint_as_float(p << SHIFT1);
            const float hi = __uint_as_float((p + 1u) << SHIFT1);
            const float w = hi * hi - lo * lo;           // square-value span
            const float f = (float)r / (float)c;
            float ev = m + 0.5f * (1.0f - f) * w;        // mean of top-f segment
            ev = fminf(ev, hi * hi);
            ev = fmaxf(ev, m);
            const float S = sAbove + (float)r * ev;
            atomicAdd(out, S * INV_KB);
        }
        cum = nc;
        sAbove += locS[j];
    }
}

// ---------------------------------------------------------------------------
extern "C" void kernel_launch(void* const* d_in, const int* in_sizes, int n_in,
                              void* d_out, int out_size, void* d_ws, size_t ws_size,
                              hipStream_t stream) {
    const float* in = (const float*)d_in[0];
    const float* lab = (const float*)d_in[1];
    float* out = (float*)d_out;

    unsigned char* w = (unsigned char*)d_ws;
    // ws layout:
    //  [0,      512 KB)  histC : 64 * 2048 u32
    //  [512 KB, 1 MB  )  histS : 64 * 2048 f32
    unsigned int* histC = (unsigned int*)(w);
    float* histS = (float*)(w + (512u << 10));

    hipMemsetAsync(w, 0, 1u << 20, stream);
    hipMemsetAsync(d_out, 0, sizeof(float), stream);

    dim3 grid(CPB, NSLICE), blk(BLK);
    k_hist<<<grid, blk, 0, stream>>>(in, lab, histC, histS);
    k_select<<<NSLICE, BLK, 0, stream>>>(histC, histS, out);
}

// Round 3
// 79.270 us; speedup vs baseline: 1.3942x; 1.3942x over previous
//
#include <hip/hip_runtime.h>
#include <stdint.h>

// Problem constants
#define NSLICE 64               // B*C
#define N_ELEM 262144           // 64^3 per slice
#define K_TOP  131072           // ceil(0.5*N)
#define INV_KB (1.0f / (131072.0f * 16.0f))

#define NB     2048             // buckets: bits 30..20 of bits(|d|)
#define SHIFT  20

// Sampling: 16 chunks of 1024 contiguous elements per slice = 1/16 of data
#define SNCH    16
#define SCHUNK  1024
#define SSTRIDE (N_ELEM / SNCH)   // 16384
#define K_S     (K_TOP / 16)      // 8192
#define MARG    640               // 10 sigma of sampled-rank noise

#define NB_W   128              // window buckets (1 KB LDS in main pass)
#define CPB    32               // blocks per slice in main pass
#define CHUNK  (N_ELEM / CPB)   // 8192
#define BLK    256

__device__ __forceinline__ unsigned int absbits(float d) {
    return __float_as_uint(d) & 0x7fffffffu;
}

// ---- 1. Sampled count histogram (1/16 of data, count-only atomics) --------
__global__ __launch_bounds__(BLK) void k_shist(const float* __restrict__ in,
                                               const float* __restrict__ lab,
                                               unsigned int* __restrict__ shist) {
    __shared__ unsigned int hc[NB];
    const int tid = threadIdx.x;
    for (int i = tid; i < NB; i += BLK) hc[i] = 0u;
    __syncthreads();

    const int slice = blockIdx.y;
#pragma unroll
    for (int j = 0; j < SNCH / 4; ++j) {    // 4 chunks per block (grid.x = 4)
        const int ch = blockIdx.x * (SNCH / 4) + j;
        const long base = (long)slice * N_ELEM + (long)ch * SSTRIDE;
        const float4 a = ((const float4*)(in + base))[tid];
        const float4 b = ((const float4*)(lab + base))[tid];
        atomicAdd(&hc[absbits(a.x - b.x) >> SHIFT], 1u);
        atomicAdd(&hc[absbits(a.y - b.y) >> SHIFT], 1u);
        atomicAdd(&hc[absbits(a.z - b.z) >> SHIFT], 1u);
        atomicAdd(&hc[absbits(a.w - b.w) >> SHIFT], 1u);
    }
    __syncthreads();
    unsigned int* g = shist + (long)slice * NB;
    for (int i = tid; i < NB; i += BLK) {
        unsigned int c = hc[i];
        if (c) atomicAdd(&g[i], c);
    }
}

// ---- 2. Pick window top bucket: first (descending) cum >= K_S - MARG ------
__global__ __launch_bounds__(BLK) void k_window(const unsigned int* __restrict__ shist,
                                                unsigned int* __restrict__ bstart) {
    const int slice = blockIdx.x;
    const unsigned int* g = shist + (long)slice * NB;
    __shared__ unsigned int part[BLK];
    __shared__ unsigned int pref[BLK];
    const int t = threadIdx.x;
    const int G = NB / BLK;   // 8 buckets/thread, descending
    unsigned int loc[NB / BLK];
    unsigned int s = 0;
#pragma unroll
    for (int j = 0; j < G; ++j) {
        loc[j] = g[NB - 1 - (t * G + j)];
        s += loc[j];
    }
    part[t] = s;
    __syncthreads();
    if (t == 0) {
        unsigned int c = 0;
        for (int i = 0; i < BLK; ++i) { pref[i] = c; c += part[i]; }
    }
    __syncthreads();
    const unsigned int target = K_S - MARG;   // 7552
    unsigned int cum = pref[t];
#pragma unroll
    for (int j = 0; j < G; ++j) {
        unsigned int nc = cum + loc[j];
        if (cum < target && nc >= target)
            bstart[slice] = (unsigned int)(NB - 1 - (t * G + j));
        cum = nc;
    }
}

// ---- 3. Main pass: register-accumulate above window; rare LDS atomics -----
__global__ __launch_bounds__(BLK) void k_main(const float* __restrict__ in,
                                              const float* __restrict__ lab,
                                              const unsigned int* __restrict__ bstart,
                                              unsigned int* __restrict__ gwc,
                                              float* __restrict__ gws,
                                              float* __restrict__ sliceS,
                                              unsigned int* __restrict__ sliceC) {
    __shared__ unsigned int hc[NB_W];
    __shared__ float hs[NB_W];
    __shared__ float redS[BLK / 64];
    __shared__ unsigned int redC[BLK / 64];
    const int tid = threadIdx.x;
    if (tid < NB_W) { hc[tid] = 0u; hs[tid] = 0.0f; }
    __syncthreads();

    const int slice = blockIdx.y;
    const int bs = (int)bstart[slice];
    const long base = (long)slice * N_ELEM + (long)blockIdx.x * CHUNK;
    const float4* a4 = (const float4*)(in + base);
    const float4* b4 = (const float4*)(lab + base);

    float S = 0.0f;
    unsigned int C = 0;
    for (int i = tid; i < CHUNK / 4; i += 2 * BLK) {   // 4 iters, 2 quads each
        float4 a0 = a4[i];
        float4 b0 = b4[i];
        float4 a1 = a4[i + BLK];
        float4 b1 = b4[i + BLK];
        float d[8] = {a0.x - b0.x, a0.y - b0.y, a0.z - b0.z, a0.w - b0.w,
                      a1.x - b1.x, a1.y - b1.y, a1.z - b1.z, a1.w - b1.w};
#pragma unroll
        for (int j = 0; j < 8; ++j) {
            const float dd = d[j];
            const float sq = dd * dd;
            const int p = (int)(absbits(dd) >> SHIFT);
            if (p > bs) {
                S += sq;
                C++;
            } else {
                const int wi = bs - p;
                if (wi < NB_W) {              // ~4% of elements
                    atomicAdd(&hc[wi], 1u);
                    atomicAdd(&hs[wi], sq);
                }
            }
        }
    }
    // wave + block reduce of exact-above accumulators
#pragma unroll
    for (int off = 32; off > 0; off >>= 1) {
        S += __shfl_down(S, off);
        C += __shfl_down(C, off);
    }
    const int lane = tid & 63, w = tid >> 6;
    if (lane == 0) { redS[w] = S; redC[w] = C; }
    __syncthreads();
    if (tid == 0) {
        float St = 0.0f;
        unsigned int Ct = 0;
        for (int i = 0; i < BLK / 64; ++i) { St += redS[i]; Ct += redC[i]; }
        atomicAdd(&sliceS[slice], St);
        atomicAdd(&sliceC[slice], Ct);
    }
    if (tid < NB_W) {
        if (hc[tid]) {
            atomicAdd(&gwc[slice * NB_W + tid], hc[tid]);
            atomicAdd(&gws[slice * NB_W + tid], hs[tid]);
        }
    }
}

// ---- 4. Final: suffix over window, interpolate partial bucket, reduce -----
__global__ __launch_bounds__(64) void k_final(const unsigned int* __restrict__ gwc,
                                              const float* __restrict__ gws,
                                              const unsigned int* __restrict__ bstart,
                                              const float* __restrict__ sliceS,
                                              const unsigned int* __restrict__ sliceC,
                                              float* __restrict__ out) {
    const int t = threadIdx.x;   // one lane per slice
    float S = sliceS[t];
    unsigned int cum = sliceC[t];
    const int bs = (int)bstart[t];
    const unsigned int* wc = gwc + t * NB_W;
    const float* ws = gws + t * NB_W;

    if (cum >= K_TOP) {
        S *= (float)K_TOP / (float)cum;       // grace: window top too low
    } else {
        bool done = false;
        for (int i = 0; i < NB_W && !done; ++i) {
            const unsigned int c = wc[i];
            if (!c) continue;
            if (cum + c >= K_TOP) {
                const unsigned int r = K_TOP - cum;
                const float m = ws[i] / (float)c;
                const int p = (bs - i) > 0 ? (bs - i) : 0;
                const float lo = __uint_as_float((unsigned int)p << SHIFT);
                const float hi = __uint_as_float((unsigned int)(p + 1) << SHIFT);
                const float span = hi * hi - lo * lo;
                const float f = (float)r / (float)c;
                float ev = m + 0.5f * (1.0f - f) * span;
                ev = fminf(ev, hi * hi);
                ev = fmaxf(ev, m);
                S += (float)r * ev;
                cum = K_TOP;
                done = true;
            } else {
                S += ws[i];
                cum += c;
            }
        }
        if (cum < K_TOP) {                     // grace: window bottom too high
            const int p = (bs - (NB_W - 1)) > 0 ? (bs - (NB_W - 1)) : 0;
            const float lo = __uint_as_float((unsigned int)p << SHIFT);
            S += (float)(K_TOP - cum) * lo * lo;
        }
    }
    // 64-lane reduce, single store
#pragma unroll
    for (int off = 32; off > 0; off >>= 1) S += __shfl_down(S, off);
    if (t == 0) out[0] = S * INV_KB;
}

// ---------------------------------------------------------------------------
extern "C" void kernel_launch(void* const* d_in, const int* in_sizes, int n_in,
                              void* d_out, int out_size, void* d_ws, size_t ws_size,
                              hipStream_t stream) {
    const float* in = (const float*)d_in[0];
    const float* lab = (const float*)d_in[1];
    float* out = (float*)d_out;

    unsigned char* w = (unsigned char*)d_ws;
    // ws layout:
    //  [0, 512K)            shist  : 64*2048 u32
    //  [512K, 512K+32K)     gwc    : 64*128 u32
    //  [+32K, +64K)         gws    : 64*128 f32
    //  [512K+64K, +256)     sliceS : 64 f32
    //  [+256, +512)         sliceC : 64 u32
    //  [+512, +768)         bstart : 64 u32   (always written by k_window)
    unsigned int* shist = (unsigned int*)(w);
    unsigned int* gwc = (unsigned int*)(w + (512u << 10));
    float* gws = (float*)(w + (512u << 10) + (32u << 10));
    float* sliceS = (float*)(w + (512u << 10) + (64u << 10));
    unsigned int* sliceC = (unsigned int*)(w + (512u << 10) + (64u << 10) + 256);
    unsigned int* bstart = (unsigned int*)(w + (512u << 10) + (64u << 10) + 512);

    hipMemsetAsync(w, 0, (512u << 10) + (64u << 10) + 512, stream);

    k_shist<<<dim3(SNCH / 4, NSLICE), BLK, 0, stream>>>(in, lab, shist);
    k_window<<<NSLICE, BLK, 0, stream>>>(shist, bstart);
    k_main<<<dim3(CPB, NSLICE), BLK, 0, stream>>>(in, lab, bstart, gwc, gws, sliceS, sliceC);
    k_final<<<1, 64, 0, stream>>>(gwc, gws, bstart, sliceS, sliceC, out);
}